// Round 1
// baseline (33210.004 us; speedup 1.0000x reference)
//
#include <hip/hip_runtime.h>
#include <stdint.h>

// ---------------- problem constants ----------------
constexpr int Bb = 128, Ss = 1024, Ii = 256, Hh = 512;
constexpr int G0n = 32, G1n = 32;           // blocks for layer0 / layer1
constexpr unsigned RING0 = 8, RING1 = 2;    // h0 / h1 ring depths

typedef _Float16 f16;
typedef _Float16 f16x8 __attribute__((ext_vector_type(8)));
typedef float f32x4 __attribute__((ext_vector_type(4)));

// ---------------- workspace layout (bytes) ----------------
constexpr size_t OFF_F0   = 0;                                   // flags layer0, (S+1) u32
constexpr size_t OFF_F1   = 8192;                                // flags layer1
constexpr size_t OFF_H0R  = 16384;                               // h0 ring fp16
constexpr size_t OFF_H1R  = OFF_H0R + (size_t)RING0 * Bb * Hh * 2;
constexpr size_t ZERO_BYTES = OFF_H1R + (size_t)RING1 * Bb * Hh * 2;
constexpr size_t OFF_X16  = (ZERO_BYTES + 255) & ~(size_t)255;   // x fp16 [S][B][I]
constexpr size_t OFF_WI0  = OFF_X16 + (size_t)Ss * Bb * Ii * 2;  // packed weights
constexpr size_t OFF_WH0  = OFF_WI0 + (size_t)3 * Hh * Ii * 2;
constexpr size_t OFF_WI1  = OFF_WH0 + (size_t)3 * Hh * Hh * 2;
constexpr size_t OFF_WH1  = OFF_WI1 + (size_t)3 * Hh * Hh * 2;
constexpr size_t WS_NEED  = OFF_WH1 + (size_t)3 * Hh * Hh * 2;

// ---------------- prologue kernels ----------------

// x [B][S][I] fp32  ->  x16 [S][B][I] fp16
__global__ void k_convert_x(const float* __restrict__ x, f16* __restrict__ x16) {
  int gid = blockIdx.x * 256 + threadIdx.x;
  int o = gid * 4;                 // linear output index over [t][b][i]
  int i = o & (Ii - 1);
  int rem = o >> 8;                // t*B + b
  int b = rem & (Bb - 1);
  int t = rem >> 7;
  const float4 v = *(const float4*)(x + ((size_t)b * Ss + t) * Ii + i);
  f16 h4[4] = { (f16)v.x, (f16)v.y, (f16)v.z, (f16)v.w };
  __builtin_memcpy(x16 + o, h4, 8);
}

// Pack W [1536][K] fp32 into MFMA B-fragment order:
// chunk gid = (nt*KS + ks)*64 + lane ; element j in 0..7 :
//   val = W[nt*16 + (lane&15)][ks*32 + (lane>>4)*8 + j]
__global__ void k_pack_w(const float* __restrict__ W, f16* __restrict__ dst, int KS) {
  int gid = blockIdx.x * 256 + threadIdx.x;
  int l  = gid & 63;
  int ks = (gid >> 6) % KS;
  int nt = (gid >> 6) / KS;
  int K  = KS * 32;
  const float* s = W + (size_t)(nt * 16 + (l & 15)) * K + ks * 32 + (l >> 4) * 8;
  f16 tmp[8];
#pragma unroll
  for (int j = 0; j < 8; ++j) tmp[j] = (f16)s[j];
  __builtin_memcpy(dst + (size_t)gid * 8, tmp, 16);
}

// ---------------- persistent GRU kernel ----------------

struct GruP {
  const f16 *x16, *wi0, *wh0, *wi1, *wh1;
  const float *bi0, *bh0, *bi1, *bh1;
  f16 *h0r, *h1r;
  unsigned *f0, *f1;
  float *out;
};

__device__ __forceinline__ f32x4 MF(f16x8 a, f16x8 b, f32x4 c) {
  return __builtin_amdgcn_mfma_f32_16x16x32_f16(a, b, c, 0, 0, 0);
}
__device__ __forceinline__ float sigmf(float x) { return 1.f / (1.f + __expf(-x)); }
__device__ __forceinline__ float tanhf_(float x) {
  float xc = fminf(8.f, fmaxf(-8.f, x));
  float e = __expf(2.f * xc);
  return (e - 1.f) / (e + 1.f);
}

// tid0 spins on device-scope flag; whole block then acquire-fences.
__device__ __forceinline__ void spin_ge(unsigned* f, unsigned tgt) {
  if (threadIdx.x == 0) {
    while (__hip_atomic_load(f, __ATOMIC_ACQUIRE, __HIP_MEMORY_SCOPE_AGENT) < tgt)
      __builtin_amdgcn_s_sleep(1);
  }
  __syncthreads();
  __threadfence();   // agent-scope: invalidate stale L1/L2 before reading ring
}

__global__ void __launch_bounds__(256) k_gru(GruP p) {
  const int tid = threadIdx.x;
  const int lane = tid & 63, wv = tid >> 6;
  const int q = lane >> 4, lc = lane & 15;
  const int g = blockIdx.x;
  if (g >= G0n + G1n) return;
  const bool L0 = (g < G0n);
  const int sl = L0 ? g : g - G0n;     // 16-column slice of H this block owns
  const int R0 = wv * 32;              // 32 batch-rows per wave (2 m-tiles)
  const int c = sl * 16 + lc;          // this lane's h column

  const float* bi = L0 ? p.bi0 : p.bi1;
  const float* bh = L0 ? p.bh0 : p.bh1;
  const float bR  = bi[c] + bh[c];
  const float bZ  = bi[Hh + c] + bh[Hh + c];
  const float bIN = bi[2 * Hh + c];
  const float bHN = bh[2 * Hh + c];

  const f16x8* wiB = (const f16x8*)(L0 ? p.wi0 : p.wi1);
  const f16x8* whB = (const f16x8*)(L0 ? p.wh0 : p.wh1);
  const int KSi = L0 ? (Ii / 32) : (Hh / 32);  // K-chunks in W_ih: 8 (layer0) / 16 (layer1)
  const int KSh = Hh / 32;                     // 16

  // fp32 master copy of this lane's h slice (C-fragment layout)
  float hold[2][4];
#pragma unroll
  for (int m = 0; m < 2; ++m)
#pragma unroll
    for (int i = 0; i < 4; ++i) hold[m][i] = 0.f;

  const f32x4 z4 = {0.f, 0.f, 0.f, 0.f};

  for (int t = 1; t <= Ss; ++t) {
    f32x4 aR[2], aZ[2], aIN[2], aHN[2];
    aR[0]=z4; aR[1]=z4; aZ[0]=z4; aZ[1]=z4;
    aIN[0]=z4; aIN[1]=z4; aHN[0]=z4; aHN[1]=z4;

    if (L0) {
      // ---- phase A (independent): gi0 = x_t @ W_ih0^T, K=256
      const f16* xa = p.x16 + (size_t)(t - 1) * Bb * Ii;
      const f16* a0p = xa + (size_t)(R0 + lc) * Ii + q * 8;
      const f16* a1p = xa + (size_t)(R0 + 16 + lc) * Ii + q * 8;
#pragma unroll 4
      for (int ks = 0; ks < Ii / 32; ++ks) {
        f16x8 a0 = *(const f16x8*)(a0p + ks * 32);
        f16x8 a1 = *(const f16x8*)(a1p + ks * 32);
        f16x8 br_ = wiB[((size_t)(0 * 32 + sl) * KSi + ks) * 64 + lane];
        f16x8 bz_ = wiB[((size_t)(1 * 32 + sl) * KSi + ks) * 64 + lane];
        f16x8 bn_ = wiB[((size_t)(2 * 32 + sl) * KSi + ks) * 64 + lane];
        aR[0]=MF(a0,br_,aR[0]);  aR[1]=MF(a1,br_,aR[1]);
        aZ[0]=MF(a0,bz_,aZ[0]);  aZ[1]=MF(a1,bz_,aZ[1]);
        aIN[0]=MF(a0,bn_,aIN[0]); aIN[1]=MF(a1,bn_,aIN[1]);
      }
      if (t >= 2) spin_ge(p.f0 + (t - 1), G0n);         // h0[t-1] ready (all 32 blocks)
      if (t >= (int)RING0 + 1) spin_ge(p.f1 + (t - RING0), G1n);  // ring backpressure
      // ---- phase B (critical): gh0 = h0[t-1] @ W_hh0^T, K=512
      const f16* ha = p.h0r + (size_t)((t - 1) & (RING0 - 1)) * Bb * Hh;
      const f16* h0p = ha + (size_t)(R0 + lc) * Hh + q * 8;
      const f16* h1p = ha + (size_t)(R0 + 16 + lc) * Hh + q * 8;
#pragma unroll 4
      for (int ks = 0; ks < KSh; ++ks) {
        f16x8 a0 = *(const f16x8*)(h0p + ks * 32);
        f16x8 a1 = *(const f16x8*)(h1p + ks * 32);
        f16x8 br_ = whB[((size_t)(0 * 32 + sl) * KSh + ks) * 64 + lane];
        f16x8 bz_ = whB[((size_t)(1 * 32 + sl) * KSh + ks) * 64 + lane];
        f16x8 bn_ = whB[((size_t)(2 * 32 + sl) * KSh + ks) * 64 + lane];
        aR[0]=MF(a0,br_,aR[0]);  aR[1]=MF(a1,br_,aR[1]);
        aZ[0]=MF(a0,bz_,aZ[0]);  aZ[1]=MF(a1,bz_,aZ[1]);
        aHN[0]=MF(a0,bn_,aHN[0]); aHN[1]=MF(a1,bn_,aHN[1]);
      }
    } else {
      if (t >= 2) spin_ge(p.f1 + (t - 1), G1n);         // h1[t-1] ready
      // ---- phase A (early): gh1 = h1[t-1] @ W_hh1^T, K=512
      const f16* ha = p.h1r + (size_t)((t - 1) & (RING1 - 1)) * Bb * Hh;
      const f16* h0p = ha + (size_t)(R0 + lc) * Hh + q * 8;
      const f16* h1p = ha + (size_t)(R0 + 16 + lc) * Hh + q * 8;
#pragma unroll 4
      for (int ks = 0; ks < KSh; ++ks) {
        f16x8 a0 = *(const f16x8*)(h0p + ks * 32);
        f16x8 a1 = *(const f16x8*)(h1p + ks * 32);
        f16x8 br_ = whB[((size_t)(0 * 32 + sl) * KSh + ks) * 64 + lane];
        f16x8 bz_ = whB[((size_t)(1 * 32 + sl) * KSh + ks) * 64 + lane];
        f16x8 bn_ = whB[((size_t)(2 * 32 + sl) * KSh + ks) * 64 + lane];
        aR[0]=MF(a0,br_,aR[0]);  aR[1]=MF(a1,br_,aR[1]);
        aZ[0]=MF(a0,bz_,aZ[0]);  aZ[1]=MF(a1,bz_,aZ[1]);
        aHN[0]=MF(a0,bn_,aHN[0]); aHN[1]=MF(a1,bn_,aHN[1]);
      }
      spin_ge(p.f0 + t, G0n);                            // wait for h0[t] from layer0
      // ---- phase B (critical): gi1 = h0[t] @ W_ih1^T, K=512
      const f16* hb = p.h0r + (size_t)(t & (RING0 - 1)) * Bb * Hh;
      const f16* g0p = hb + (size_t)(R0 + lc) * Hh + q * 8;
      const f16* g1p = hb + (size_t)(R0 + 16 + lc) * Hh + q * 8;
#pragma unroll 4
      for (int ks = 0; ks < KSh; ++ks) {
        f16x8 a0 = *(const f16x8*)(g0p + ks * 32);
        f16x8 a1 = *(const f16x8*)(g1p + ks * 32);
        f16x8 br_ = wiB[((size_t)(0 * 32 + sl) * 16 + ks) * 64 + lane];
        f16x8 bz_ = wiB[((size_t)(1 * 32 + sl) * 16 + ks) * 64 + lane];
        f16x8 bn_ = wiB[((size_t)(2 * 32 + sl) * 16 + ks) * 64 + lane];
        aR[0]=MF(a0,br_,aR[0]);  aR[1]=MF(a1,br_,aR[1]);
        aZ[0]=MF(a0,bz_,aZ[0]);  aZ[1]=MF(a1,bz_,aZ[1]);
        aIN[0]=MF(a0,bn_,aIN[0]); aIN[1]=MF(a1,bn_,aIN[1]);
      }
    }

    // ---- epilogue: gates + state update + publish
    f16* hw = L0 ? (p.h0r + (size_t)(t & (RING0 - 1)) * Bb * Hh)
                 : (p.h1r + (size_t)(t & (RING1 - 1)) * Bb * Hh);
#pragma unroll
    for (int m = 0; m < 2; ++m) {
#pragma unroll
      for (int i = 0; i < 4; ++i) {
        float r = sigmf(aR[m][i] + bR);
        float z = sigmf(aZ[m][i] + bZ);
        float n = tanhf_(aIN[m][i] + bIN + r * (aHN[m][i] + bHN));
        float h = (1.f - z) * n + z * hold[m][i];
        hold[m][i] = h;
        int row = R0 + m * 16 + q * 4 + i;   // C-frag: col=lane&15, row=(lane>>4)*4+i
        hw[(size_t)row * Hh + c] = (f16)h;
        if (!L0) {
          p.out[(size_t)row * Ss * Hh + (size_t)(t - 1) * Hh + c] = h;
          if (t == Ss) p.out[(size_t)Bb * Ss * Hh + (size_t)row * Hh + c] = h;
        }
      }
    }
    __threadfence();   // release: drain stores + write back L2 device-wide
    __syncthreads();
    if (tid == 0)
      __hip_atomic_fetch_add((L0 ? p.f0 : p.f1) + t, 1u,
                             __ATOMIC_RELEASE, __HIP_MEMORY_SCOPE_AGENT);
  }
}

// ---------------- host launcher ----------------

extern "C" void kernel_launch(void* const* d_in, const int* in_sizes, int n_in,
                              void* d_out, int out_size, void* d_ws, size_t ws_size,
                              hipStream_t stream) {
  (void)in_sizes; (void)n_in; (void)out_size;
  const float* x    = (const float*)d_in[0];
  const float* wih0 = (const float*)d_in[1];
  const float* whh0 = (const float*)d_in[2];
  const float* bih0 = (const float*)d_in[3];
  const float* bhh0 = (const float*)d_in[4];
  const float* wih1 = (const float*)d_in[5];
  const float* whh1 = (const float*)d_in[6];
  const float* bih1 = (const float*)d_in[7];
  const float* bhh1 = (const float*)d_in[8];
  char* ws = (char*)d_ws;
  if (ws_size < WS_NEED) return;  // workspace too small: fail visibly

  // zero flags + h rings (t=0 state == 0)
  hipMemsetAsync(ws, 0, ZERO_BYTES, stream);
  // x -> fp16 time-major
  hipLaunchKernelGGL(k_convert_x, dim3(32768), dim3(256), 0, stream,
                     x, (f16*)(ws + OFF_X16));
  // weights -> MFMA B-fragment packs
  hipLaunchKernelGGL(k_pack_w, dim3(192), dim3(256), 0, stream, wih0, (f16*)(ws + OFF_WI0), 8);
  hipLaunchKernelGGL(k_pack_w, dim3(384), dim3(256), 0, stream, whh0, (f16*)(ws + OFF_WH0), 16);
  hipLaunchKernelGGL(k_pack_w, dim3(384), dim3(256), 0, stream, wih1, (f16*)(ws + OFF_WI1), 16);
  hipLaunchKernelGGL(k_pack_w, dim3(384), dim3(256), 0, stream, whh1, (f16*)(ws + OFF_WH1), 16);

  GruP prm;
  prm.x16 = (const f16*)(ws + OFF_X16);
  prm.wi0 = (const f16*)(ws + OFF_WI0);
  prm.wh0 = (const f16*)(ws + OFF_WH0);
  prm.wi1 = (const f16*)(ws + OFF_WI1);
  prm.wh1 = (const f16*)(ws + OFF_WH1);
  prm.bi0 = bih0; prm.bh0 = bhh0; prm.bi1 = bih1; prm.bh1 = bhh1;
  prm.h0r = (f16*)(ws + OFF_H0R);
  prm.h1r = (f16*)(ws + OFF_H1R);
  prm.f0  = (unsigned*)(ws + OFF_F0);
  prm.f1  = (unsigned*)(ws + OFF_F1);
  prm.out = (float*)d_out;

  void* kp[1] = { &prm };
  hipLaunchCooperativeKernel((const void*)k_gru, dim3(G0n + G1n), dim3(256),
                             kp, 0, stream);
}

// Round 2
// 24732.541 us; speedup vs baseline: 1.3428x; 1.3428x over previous
//
#include <hip/hip_runtime.h>
#include <stdint.h>

// ---------------- problem constants ----------------
constexpr int Bb = 128, Ss = 1024, Ii = 256, Hh = 512;
constexpr unsigned RING0 = 8, RING1 = 2;    // h0 / h1 ring depths

typedef _Float16 f16;
typedef _Float16 f16x8 __attribute__((ext_vector_type(8)));
typedef float f32x4 __attribute__((ext_vector_type(4)));
typedef unsigned long long u64;

// ---------------- workspace layout (bytes) ----------------
// flags: per (t, producer-block) word, t in [0..S], 32 producers per layer
constexpr size_t OFF_F0   = 0;                                   // (S+1)*32 u32 = 131200
constexpr size_t OFF_F1   = 135168;
constexpr size_t OFF_H0R  = 270336;                              // h0 ring fp16 [RING0][B][H]
constexpr size_t OFF_H1R  = OFF_H0R + (size_t)RING0 * Bb * Hh * 2;
constexpr size_t ZERO_BYTES = OFF_H1R + (size_t)RING1 * Bb * Hh * 2;
constexpr size_t OFF_X16  = (ZERO_BYTES + 255) & ~(size_t)255;   // x fp16 [S][B][I]
constexpr size_t OFF_WI0  = OFF_X16 + (size_t)Ss * Bb * Ii * 2;  // packed weights
constexpr size_t OFF_WH0  = OFF_WI0 + (size_t)3 * Hh * Ii * 2;
constexpr size_t OFF_WI1  = OFF_WH0 + (size_t)3 * Hh * Hh * 2;
constexpr size_t OFF_WH1  = OFF_WI1 + (size_t)3 * Hh * Hh * 2;
constexpr size_t WS_NEED  = OFF_WH1 + (size_t)3 * Hh * Hh * 2;

// ---------------- prologue kernels ----------------

// x [B][S][I] fp32  ->  x16 [S][B][I] fp16
__global__ void k_convert_x(const float* __restrict__ x, f16* __restrict__ x16) {
  int gid = blockIdx.x * 256 + threadIdx.x;
  int o = gid * 4;                 // linear output index over [t][b][i]
  int i = o & (Ii - 1);
  int rem = o >> 8;                // t*B + b
  int b = rem & (Bb - 1);
  int t = rem >> 7;
  const float4 v = *(const float4*)(x + ((size_t)b * Ss + t) * Ii + i);
  f16 h4[4] = { (f16)v.x, (f16)v.y, (f16)v.z, (f16)v.w };
  __builtin_memcpy(x16 + o, h4, 8);
}

// Pack W [1536][K] fp32 into MFMA B-fragment order:
// chunk gid = (nt*KS + ks)*64 + lane ; element j in 0..7 :
//   val = W[nt*16 + (lane&15)][ks*32 + (lane>>4)*8 + j]
__global__ void k_pack_w(const float* __restrict__ W, f16* __restrict__ dst, int KS) {
  int gid = blockIdx.x * 256 + threadIdx.x;
  int l  = gid & 63;
  int ks = (gid >> 6) % KS;
  int nt = (gid >> 6) / KS;
  int K  = KS * 32;
  const float* s = W + (size_t)(nt * 16 + (l & 15)) * K + ks * 32 + (l >> 4) * 8;
  f16 tmp[8];
#pragma unroll
  for (int j = 0; j < 8; ++j) tmp[j] = (f16)s[j];
  __builtin_memcpy(dst + (size_t)gid * 8, tmp, 16);
}

// ---------------- persistent GRU kernel ----------------

struct GruP {
  const f16 *x16, *wi0, *wh0, *wi1, *wh1;
  const float *bi0, *bh0, *bi1, *bh1;
  f16 *h0r, *h1r;
  unsigned *f0, *f1;
  float *out;
};

__device__ __forceinline__ f32x4 MF(f16x8 a, f16x8 b, f32x4 c) {
  return __builtin_amdgcn_mfma_f32_16x16x32_f16(a, b, c, 0, 0, 0);
}
__device__ __forceinline__ float sigmf(float x) { return 1.f / (1.f + __expf(-x)); }
__device__ __forceinline__ float tanhf_(float x) {
  float xc = fminf(8.f, fmaxf(-8.f, x));
  float e = __expf(2.f * xc);
  return (e - 1.f) / (e + 1.f);
}

// Uncached (agent-scope, L1/L2-bypassing) 16-byte ring load as 2x u64 relaxed atomics.
__device__ __forceinline__ f16x8 ldA(const f16* p) {
  union { u64 q[2]; f16x8 v; } u;
  u.q[0] = __hip_atomic_load((const u64*)p,     __ATOMIC_RELAXED, __HIP_MEMORY_SCOPE_AGENT);
  u.q[1] = __hip_atomic_load((const u64*)p + 1, __ATOMIC_RELAXED, __HIP_MEMORY_SCOPE_AGENT);
  return u.v;
}

// Wait until all 32 per-producer flags for one step are set.
// Lanes 0..31 each poll one word; no RMW, no bulk cache ops.
__device__ __forceinline__ void wait32(const unsigned* fl) {
  int l = threadIdx.x;
  if (l < 32) {
    while (__hip_atomic_load(fl + l, __ATOMIC_RELAXED, __HIP_MEMORY_SCOPE_AGENT) == 0u)
      __builtin_amdgcn_s_sleep(1);
  }
  __syncthreads();
}

__global__ void __launch_bounds__(256) k_gru(GruP p) {
  const int tid = threadIdx.x;
  const int lane = tid & 63, wv = tid >> 6;
  const int q = lane >> 4, lc = lane & 15;
  const int g = blockIdx.x;
  if (g >= 64) return;
  // XCD-locality swizzle (performance heuristic only): blocks land on XCD g&7
  // round-robin; give layer0 XCDs 0-3, layer1 XCDs 4-7 so each XCD's weight
  // working set (<=3 MB) fits its 4 MB L2.
  const bool L0 = ((g & 7) < 4);
  const int sl = (g >> 3) * 4 + (g & 3);   // 16-column slice of H this block owns
  const int R0 = wv * 32;                  // 32 batch-rows per wave (2 m-tiles)
  const int c = sl * 16 + lc;              // this lane's h column

  const float* bi = L0 ? p.bi0 : p.bi1;
  const float* bh = L0 ? p.bh0 : p.bh1;
  const float bR  = bi[c] + bh[c];
  const float bZ  = bi[Hh + c] + bh[Hh + c];
  const float bIN = bi[2 * Hh + c];
  const float bHN = bh[2 * Hh + c];

  const f16x8* wiB = (const f16x8*)(L0 ? p.wi0 : p.wi1);
  const f16x8* whB = (const f16x8*)(L0 ? p.wh0 : p.wh1);
  const int KSi = L0 ? (Ii / 32) : (Hh / 32);  // K-chunks in W_ih: 8 (L0) / 16 (L1)
  const int KSh = Hh / 32;                     // 16

  // fp32 master copy of this lane's h slice (C-fragment layout)
  float hold[2][4];
#pragma unroll
  for (int m = 0; m < 2; ++m)
#pragma unroll
    for (int i = 0; i < 4; ++i) hold[m][i] = 0.f;

  const f32x4 z4 = {0.f, 0.f, 0.f, 0.f};

  for (int t = 1; t <= Ss; ++t) {
    f32x4 aR[2], aZ[2], aIN[2], aHN[2];
    aR[0]=z4; aR[1]=z4; aZ[0]=z4; aZ[1]=z4;
    aIN[0]=z4; aIN[1]=z4; aHN[0]=z4; aHN[1]=z4;

    if (L0) {
      // ---- phase A (independent): gi0 = x_t @ W_ih0^T, K=256 (cached loads)
      const f16* xa = p.x16 + (size_t)(t - 1) * Bb * Ii;
      const f16* a0p = xa + (size_t)(R0 + lc) * Ii + q * 8;
      const f16* a1p = xa + (size_t)(R0 + 16 + lc) * Ii + q * 8;
#pragma unroll 4
      for (int ks = 0; ks < Ii / 32; ++ks) {
        f16x8 a0 = *(const f16x8*)(a0p + ks * 32);
        f16x8 a1 = *(const f16x8*)(a1p + ks * 32);
        f16x8 br_ = wiB[((size_t)(0 * 32 + sl) * KSi + ks) * 64 + lane];
        f16x8 bz_ = wiB[((size_t)(1 * 32 + sl) * KSi + ks) * 64 + lane];
        f16x8 bn_ = wiB[((size_t)(2 * 32 + sl) * KSi + ks) * 64 + lane];
        aR[0]=MF(a0,br_,aR[0]);  aR[1]=MF(a1,br_,aR[1]);
        aZ[0]=MF(a0,bz_,aZ[0]);  aZ[1]=MF(a1,bz_,aZ[1]);
        aIN[0]=MF(a0,bn_,aIN[0]); aIN[1]=MF(a1,bn_,aIN[1]);
      }
      if (t >= 2) wait32(p.f0 + (size_t)(t - 1) * 32);             // h0[t-1] ready
      if (t > (int)RING0) wait32(p.f1 + (size_t)(t - RING0) * 32); // ring backpressure
      // ---- phase B (critical): gh0 = h0[t-1] @ W_hh0^T, K=512 (uncached ring loads)
      const f16* ha = p.h0r + (size_t)((t - 1) & (RING0 - 1)) * Bb * Hh;
      const f16* h0p = ha + (size_t)(R0 + lc) * Hh + q * 8;
      const f16* h1p = ha + (size_t)(R0 + 16 + lc) * Hh + q * 8;
#pragma unroll 4
      for (int ks = 0; ks < KSh; ++ks) {
        f16x8 a0 = ldA(h0p + ks * 32);
        f16x8 a1 = ldA(h1p + ks * 32);
        f16x8 br_ = whB[((size_t)(0 * 32 + sl) * KSh + ks) * 64 + lane];
        f16x8 bz_ = whB[((size_t)(1 * 32 + sl) * KSh + ks) * 64 + lane];
        f16x8 bn_ = whB[((size_t)(2 * 32 + sl) * KSh + ks) * 64 + lane];
        aR[0]=MF(a0,br_,aR[0]);  aR[1]=MF(a1,br_,aR[1]);
        aZ[0]=MF(a0,bz_,aZ[0]);  aZ[1]=MF(a1,bz_,aZ[1]);
        aHN[0]=MF(a0,bn_,aHN[0]); aHN[1]=MF(a1,bn_,aHN[1]);
      }
    } else {
      if (t >= 2) wait32(p.f1 + (size_t)(t - 1) * 32);             // h1[t-1] ready
      // ---- phase A (early): gh1 = h1[t-1] @ W_hh1^T, K=512
      const f16* ha = p.h1r + (size_t)((t - 1) & (RING1 - 1)) * Bb * Hh;
      const f16* h0p = ha + (size_t)(R0 + lc) * Hh + q * 8;
      const f16* h1p = ha + (size_t)(R0 + 16 + lc) * Hh + q * 8;
#pragma unroll 4
      for (int ks = 0; ks < KSh; ++ks) {
        f16x8 a0 = ldA(h0p + ks * 32);
        f16x8 a1 = ldA(h1p + ks * 32);
        f16x8 br_ = whB[((size_t)(0 * 32 + sl) * KSh + ks) * 64 + lane];
        f16x8 bz_ = whB[((size_t)(1 * 32 + sl) * KSh + ks) * 64 + lane];
        f16x8 bn_ = whB[((size_t)(2 * 32 + sl) * KSh + ks) * 64 + lane];
        aR[0]=MF(a0,br_,aR[0]);  aR[1]=MF(a1,br_,aR[1]);
        aZ[0]=MF(a0,bz_,aZ[0]);  aZ[1]=MF(a1,bz_,aZ[1]);
        aHN[0]=MF(a0,bn_,aHN[0]); aHN[1]=MF(a1,bn_,aHN[1]);
      }
      wait32(p.f0 + (size_t)t * 32);                               // h0[t] from layer0
      // ---- phase B (critical): gi1 = h0[t] @ W_ih1^T, K=512
      const f16* hb = p.h0r + (size_t)(t & (RING0 - 1)) * Bb * Hh;
      const f16* g0p = hb + (size_t)(R0 + lc) * Hh + q * 8;
      const f16* g1p = hb + (size_t)(R0 + 16 + lc) * Hh + q * 8;
#pragma unroll 4
      for (int ks = 0; ks < KSh; ++ks) {
        f16x8 a0 = ldA(g0p + ks * 32);
        f16x8 a1 = ldA(g1p + ks * 32);
        f16x8 br_ = wiB[((size_t)(0 * 32 + sl) * 16 + ks) * 64 + lane];
        f16x8 bz_ = wiB[((size_t)(1 * 32 + sl) * 16 + ks) * 64 + lane];
        f16x8 bn_ = wiB[((size_t)(2 * 32 + sl) * 16 + ks) * 64 + lane];
        aR[0]=MF(a0,br_,aR[0]);  aR[1]=MF(a1,br_,aR[1]);
        aZ[0]=MF(a0,bz_,aZ[0]);  aZ[1]=MF(a1,bz_,aZ[1]);
        aIN[0]=MF(a0,bn_,aIN[0]); aIN[1]=MF(a1,bn_,aIN[1]);
      }
    }

    // ---- epilogue: gates + state update + publish
    f16* hw = L0 ? (p.h0r + (size_t)(t & (RING0 - 1)) * Bb * Hh)
                 : (p.h1r + (size_t)(t & (RING1 - 1)) * Bb * Hh);
#pragma unroll
    for (int m = 0; m < 2; ++m) {
#pragma unroll
      for (int i = 0; i < 4; ++i) {
        float r = sigmf(aR[m][i] + bR);
        float z = sigmf(aZ[m][i] + bZ);
        float n = tanhf_(aIN[m][i] + bIN + r * (aHN[m][i] + bHN));
        float h = (1.f - z) * n + z * hold[m][i];
        hold[m][i] = h;
        int row = R0 + m * 16 + q * 4 + i;   // C-frag: col=lane&15, row=(lane>>4)*4+i
        // pair adjacent columns (lanes lc, lc^1 share the same row) -> one
        // 32-bit write-through atomic store, guaranteed lock-free.
        union { f16 hv; unsigned short us; } cv; cv.hv = (f16)h;
        unsigned mine = cv.us;
        unsigned other = __shfl_xor((int)mine, 1, 64);
        if (!(lane & 1)) {
          unsigned word = mine | (other << 16);
          __hip_atomic_store((unsigned*)((unsigned short*)hw + (size_t)row * Hh + c),
                             word, __ATOMIC_RELAXED, __HIP_MEMORY_SCOPE_AGENT);
        }
        if (!L0) {
          __builtin_nontemporal_store(h, &p.out[(size_t)row * Ss * Hh + (size_t)(t - 1) * Hh + c]);
          if (t == Ss)
            __builtin_nontemporal_store(h, &p.out[(size_t)Bb * Ss * Hh + (size_t)row * Hh + c]);
        }
      }
    }
    // publish: drain this wave's write-through stores, barrier (=> all waves
    // drained), then set this block's per-step flag. No bulk cache ops.
    __atomic_signal_fence(__ATOMIC_SEQ_CST);
    __builtin_amdgcn_s_waitcnt(0);
    __atomic_signal_fence(__ATOMIC_SEQ_CST);
    __syncthreads();
    if (tid == 0)
      __hip_atomic_store((L0 ? p.f0 : p.f1) + (size_t)t * 32 + sl, 1u,
                         __ATOMIC_RELAXED, __HIP_MEMORY_SCOPE_AGENT);
  }
}

// ---------------- host launcher ----------------

extern "C" void kernel_launch(void* const* d_in, const int* in_sizes, int n_in,
                              void* d_out, int out_size, void* d_ws, size_t ws_size,
                              hipStream_t stream) {
  (void)in_sizes; (void)n_in; (void)out_size;
  const float* x    = (const float*)d_in[0];
  const float* wih0 = (const float*)d_in[1];
  const float* whh0 = (const float*)d_in[2];
  const float* bih0 = (const float*)d_in[3];
  const float* bhh0 = (const float*)d_in[4];
  const float* wih1 = (const float*)d_in[5];
  const float* whh1 = (const float*)d_in[6];
  const float* bih1 = (const float*)d_in[7];
  const float* bhh1 = (const float*)d_in[8];
  char* ws = (char*)d_ws;
  if (ws_size < WS_NEED) return;  // workspace too small: fail visibly

  // zero flags + h rings (t=0 state == 0)
  hipMemsetAsync(ws, 0, ZERO_BYTES, stream);
  // x -> fp16 time-major
  hipLaunchKernelGGL(k_convert_x, dim3(32768), dim3(256), 0, stream,
                     x, (f16*)(ws + OFF_X16));
  // weights -> MFMA B-fragment packs
  hipLaunchKernelGGL(k_pack_w, dim3(192), dim3(256), 0, stream, wih0, (f16*)(ws + OFF_WI0), 8);
  hipLaunchKernelGGL(k_pack_w, dim3(384), dim3(256), 0, stream, whh0, (f16*)(ws + OFF_WH0), 16);
  hipLaunchKernelGGL(k_pack_w, dim3(384), dim3(256), 0, stream, wih1, (f16*)(ws + OFF_WI1), 16);
  hipLaunchKernelGGL(k_pack_w, dim3(384), dim3(256), 0, stream, whh1, (f16*)(ws + OFF_WH1), 16);

  GruP prm;
  prm.x16 = (const f16*)(ws + OFF_X16);
  prm.wi0 = (const f16*)(ws + OFF_WI0);
  prm.wh0 = (const f16*)(ws + OFF_WH0);
  prm.wi1 = (const f16*)(ws + OFF_WI1);
  prm.wh1 = (const f16*)(ws + OFF_WH1);
  prm.bi0 = bih0; prm.bh0 = bhh0; prm.bi1 = bih1; prm.bh1 = bhh1;
  prm.h0r = (f16*)(ws + OFF_H0R);
  prm.h1r = (f16*)(ws + OFF_H1R);
  prm.f0  = (unsigned*)(ws + OFF_F0);
  prm.f1  = (unsigned*)(ws + OFF_F1);
  prm.out = (float*)d_out;

  void* kp[1] = { &prm };
  hipLaunchCooperativeKernel((const void*)k_gru, dim3(64), dim3(256),
                             kp, 0, stream);
}